// Round 13
// baseline (59.677 us; speedup 1.0000x reference)
//
#include <hip/hip_runtime.h>

#define DD 128
#define KADJ 12
#define BN_TOTAL 12800
#define RTOT (BN_TOTAL * KADJ)      // 153600 flat A-rows
#define NTILE (RTOT / 16)           // 9600 16-row tiles

typedef float f32x4 __attribute__((ext_vector_type(4)));
typedef float f32x2 __attribute__((ext_vector_type(2)));
typedef __bf16 bf16x8 __attribute__((ext_vector_type(8)));

__device__ __forceinline__ bf16x8 cvt8(f32x4 a, f32x4 b) {
    bf16x8 r;
    r[0] = (__bf16)a[0]; r[1] = (__bf16)a[1]; r[2] = (__bf16)a[2]; r[3] = (__bf16)a[3];
    r[4] = (__bf16)b[0]; r[5] = (__bf16)b[1]; r[6] = (__bf16)b[2]; r[7] = (__bf16)b[3];
    return r;
}

// ---- K0: shuffle w1 (rows 0..127) and w3 into MFMA B-fragment order, bf16 ----
__global__ void k_prep(const float* __restrict__ w1, const float* __restrict__ w3,
                       __bf16* __restrict__ w1f, __bf16* __restrict__ w3f) {
    int idx = blockIdx.x * 256 + threadIdx.x;   // 0..49151
    int lane = (idx >> 3) & 63, e = idx & 7;
    int l = lane & 15, gg = lane >> 4;
    if (idx < 16384) {
        int fi = idx >> 9, n = fi >> 2, ks = fi & 3;
        int k = ks * 32 + gg * 8 + e;
        w1f[idx] = (__bf16)w1[k * DD + n * 16 + l];
    } else {
        int j = idx - 16384;
        int fi = j >> 9, n = fi >> 3, ks = fi & 7;
        int k = ks * 32 + gg * 8 + e;
        w3f[j] = (__bf16)w3[k * DD + n * 16 + l];
    }
}

// ---- K1a: scores GEMM over flat A[153600x128]. B resident in VGPRs, loaded once
// per wave, amortized over ~4.7 tiles (grid-stride). No LDS, no barriers, no pad.
__launch_bounds__(256, 2)
__global__ void k_sco(const float* __restrict__ ave, const float* __restrict__ adj,
                      const float* __restrict__ wgt, const float* __restrict__ w1,
                      const float* __restrict__ w2, const __bf16* __restrict__ w1f,
                      float* __restrict__ sco) {
    const int lane = threadIdx.x & 63;
    const int w = threadIdx.x >> 6;
    const int l = lane & 15, g = lane >> 4;
    const int NW = gridDim.x * 4;              // total waves
    int wid = blockIdx.x * 4 + w;

    // B fragments: whole w1 in 64 VGPRs (coalesced 1KB wave loads, once per wave)
    bf16x8 bfr[4][8];
    #pragma unroll
    for (int ks = 0; ks < 4; ++ks)
        #pragma unroll
        for (int n = 0; n < 8; ++n)
            bfr[ks][n] = *reinterpret_cast<const bf16x8*>(
                w1f + ((size_t)(n * 4 + ks) * 512 + lane * 8));

    // loop-invariant epilogue operands
    float w1r[8], w2v[8];
    #pragma unroll
    for (int n = 0; n < 8; ++n) {
        w1r[n] = w1[128 * DD + n * 16 + l];    // w1 row 128 = concat'd wgt row
        w2v[n] = w2[n * 16 + l];
    }

    f32x4 pa[8];                               // A prefetch (lane's row, 32B x 4 ks)
    #define ISSUE_A(TILE) do {                                                   \
        const float* ar_ = adj + ((size_t)(TILE) * 16 + l) * DD + g * 8;         \
        _Pragma("unroll")                                                        \
        for (int s_ = 0; s_ < 4; ++s_) {                                         \
            pa[2 * s_]     = *reinterpret_cast<const f32x4*>(ar_ + s_ * 32);     \
            pa[2 * s_ + 1] = *reinterpret_cast<const f32x4*>(ar_ + s_ * 32 + 4); \
        }                                                                        \
    } while (0)

    if (wid < NTILE) ISSUE_A(wid);
    #pragma unroll 1
    for (int tile = wid; tile < NTILE; tile += NW) {
        // consume prefetched A: af = bf16(ave * adj)
        const unsigned lr = (unsigned)(tile * 16 + l);
        const float* er = ave + (size_t)(lr / 12u) * DD + g * 8;
        bf16x8 af[4];
        #pragma unroll
        for (int s = 0; s < 4; ++s) {
            f32x4 e0 = *reinterpret_cast<const f32x4*>(er + s * 32);
            f32x4 e1 = *reinterpret_cast<const f32x4*>(er + s * 32 + 4);
            af[s] = cvt8(pa[2 * s] * e0, pa[2 * s + 1] * e1);
        }
        int next = tile + NW;
        if (next < NTILE) ISSUE_A(next);       // hide under MFMA + epilogue

        f32x4 acc[8];
        #pragma unroll
        for (int n = 0; n < 8; ++n) acc[n] = f32x4{0.f, 0.f, 0.f, 0.f};
        #pragma unroll
        for (int ks = 0; ks < 4; ++ks)
            #pragma unroll
            for (int n = 0; n < 8; ++n)
                acc[n] = __builtin_amdgcn_mfma_f32_16x16x32_bf16(
                    af[ks], bfr[ks][n], acc[n], 0, 0, 0);

        // epilogue: rank-1 wgt col, leaky, dot w2. acc[n][j]=h[row g*4+j][col n*16+l]
        float wv[4];
        #pragma unroll
        for (int j = 0; j < 4; ++j) wv[j] = wgt[(size_t)tile * 16 + g * 4 + j];
        float p[4] = {0.f, 0.f, 0.f, 0.f};
        #pragma unroll
        for (int n = 0; n < 8; ++n) {
            #pragma unroll
            for (int j = 0; j < 4; ++j) {
                float h = fmaf(wv[j], w1r[n], acc[n][j]);
                h = h > 0.f ? h : 0.2f * h;
                p[j] = fmaf(h, w2v[n], p[j]);
            }
        }
        #pragma unroll
        for (int j = 0; j < 4; ++j) {
            p[j] += __shfl_xor(p[j], 1, 64);
            p[j] += __shfl_xor(p[j], 2, 64);
            p[j] += __shfl_xor(p[j], 4, 64);
            p[j] += __shfl_xor(p[j], 8, 64);
        }
        if (l == 0)
            *reinterpret_cast<f32x4*>(sco + (size_t)tile * 16 + g * 4) =
                f32x4{p[0], p[1], p[2], p[3]};
    }
    #undef ISSUE_A
}

// ---- K1b: softmax + att. 1 wave per bn, pure streaming, no MFMA/LDS/shfl. ----
__launch_bounds__(256)
__global__ void k_att2(const float* __restrict__ adj, const float* __restrict__ sco,
                       float* __restrict__ att_out) {
    const int lane = threadIdx.x & 63;
    const int w = threadIdx.x >> 6;
    const int bn = blockIdx.x * 4 + w;

    const float* s = sco + (size_t)bn * KADJ;  // wave-uniform -> scalar loads
    float sv[KADJ];
    float mx = -1e30f;
    #pragma unroll
    for (int k = 0; k < KADJ; ++k) { sv[k] = s[k]; mx = fmaxf(mx, sv[k]); }
    float ssum = 0.f;
    #pragma unroll
    for (int k = 0; k < KADJ; ++k) { sv[k] = __expf(sv[k] - mx); ssum += sv[k]; }
    float inv = 1.f / ssum;

    const float* adjp = adj + (size_t)bn * (KADJ * DD);
    float a0 = 0.f, a1 = 0.f;
    #pragma unroll
    for (int k = 0; k < KADJ; ++k) {
        float alpha = sv[k] * inv;
        a0 = fmaf(alpha, adjp[k * DD + lane], a0);
        a1 = fmaf(alpha, adjp[k * DD + 64 + lane], a1);
    }
    att_out[(size_t)bn * DD + lane] = a0;
    att_out[(size_t)bn * DD + 64 + lane] = a1;
}

// ---- K2: out = relu([itm | att] @ w3) via MFMA; B-frags coalesced from w3f ----
__launch_bounds__(256)
__global__ void k_out(const float* __restrict__ itm, const float* att,
                      const __bf16* __restrict__ w3f, float* outp) {
    const int t = threadIdx.x;
    const int lane = t & 63;
    const int w = t >> 6;
    const int l = lane & 15, g = lane >> 4;
    const int R0 = blockIdx.x * 64 + w * 16;
    const int row = R0 + l;

    bf16x8 afr[8];
    const float* ip = itm + (size_t)row * DD;
    #pragma unroll
    for (int s = 0; s < 4; ++s) {
        int c = s * 32 + g * 8;
        f32x4 a0 = *reinterpret_cast<const f32x4*>(ip + c);
        f32x4 a1 = *reinterpret_cast<const f32x4*>(ip + c + 4);
        afr[s] = cvt8(a0, a1);
    }
    const float* ap = att + (size_t)row * DD;
    #pragma unroll
    for (int s = 0; s < 4; ++s) {
        int c = s * 32 + g * 8;
        f32x4 a0 = *reinterpret_cast<const f32x4*>(ap + c);
        f32x4 a1 = *reinterpret_cast<const f32x4*>(ap + c + 4);
        afr[4 + s] = cvt8(a0, a1);
    }

    f32x4 acc[8];
    #pragma unroll
    for (int n = 0; n < 8; ++n) acc[n] = f32x4{0.f, 0.f, 0.f, 0.f};
    #pragma unroll
    for (int s = 0; s < 8; ++s) {
        const __bf16* bp = w3f + ((size_t)s * 64 + lane) * 8;    // coalesced 1KB/wave
        #pragma unroll
        for (int n = 0; n < 8; ++n) {
            bf16x8 bfr = *reinterpret_cast<const bf16x8*>(bp + (size_t)n * 4096);
            acc[n] = __builtin_amdgcn_mfma_f32_16x16x32_bf16(afr[s], bfr, acc[n], 0, 0, 0);
        }
    }

    #pragma unroll
    for (int n = 0; n < 8; ++n) {
        #pragma unroll
        for (int j = 0; j < 4; ++j)
            outp[(size_t)(R0 + g * 4 + j) * DD + n * 16 + l] = fmaxf(acc[n][j], 0.f);
    }
}

extern "C" void kernel_launch(void* const* d_in, const int* in_sizes, int n_in,
                              void* d_out, int out_size, void* d_ws, size_t ws_size,
                              hipStream_t stream) {
    const float* itm = (const float*)d_in[1];
    const float* ave = (const float*)d_in[2];
    const float* adj = (const float*)d_in[3];
    const float* wgt = (const float*)d_in[4];
    const float* w1  = (const float*)d_in[5];
    const float* w2  = (const float*)d_in[6];
    const float* w3  = (const float*)d_in[7];
    float* outp = (float*)d_out;

    __bf16* w1f = (__bf16*)d_ws;                        // 32 KB, fragment-ordered
    __bf16* w3f = (__bf16*)((char*)d_ws + 32 * 1024);   // 64 KB, fragment-ordered
    float* sco  = (float*)((char*)d_ws + 96 * 1024);    // 153600 f32 = 614 KB

    k_prep<<<dim3(192), dim3(256), 0, stream>>>(w1, w3, w1f, w3f);
    k_sco<<<dim3(512), dim3(256), 0, stream>>>(ave, adj, wgt, w1, w2, w1f, sco);
    k_att2<<<dim3(BN_TOTAL / 4), dim3(256), 0, stream>>>(adj, sco, outp);
    k_out<<<dim3(BN_TOTAL / 64), dim3(256), 0, stream>>>(itm, outp, w3f, outp);
}

// Round 14
// 48.571 us; speedup vs baseline: 1.2287x; 1.2287x over previous
//
#include <hip/hip_runtime.h>

#define DD 128
#define KADJ 12
#define BN_TOTAL 12800

typedef float f32x4 __attribute__((ext_vector_type(4)));
typedef float f32x2 __attribute__((ext_vector_type(2)));
typedef __bf16 bf16x8 __attribute__((ext_vector_type(8)));
typedef unsigned int u32;

__device__ __forceinline__ bf16x8 cvt8(f32x4 a, f32x4 b) {
    bf16x8 r;
    r[0] = (__bf16)a[0]; r[1] = (__bf16)a[1]; r[2] = (__bf16)a[2]; r[3] = (__bf16)a[3];
    r[4] = (__bf16)b[0]; r[5] = (__bf16)b[1]; r[6] = (__bf16)b[2]; r[7] = (__bf16)b[3];
    return r;
}

__device__ __forceinline__ bf16x8 mul8(bf16x8 a, bf16x8 b) {
    bf16x8 r;
    #pragma unroll
    for (int i = 0; i < 8; ++i) r[i] = (__bf16)((float)a[i] * (float)b[i]);
    return r;
}

// ---- K0: shuffle w1 (rows 0..127) and w3 into MFMA B-fragment order, bf16 ----
__global__ void k_prep(const float* __restrict__ w1, const float* __restrict__ w3,
                       __bf16* __restrict__ w1f, __bf16* __restrict__ w3f) {
    int idx = blockIdx.x * 256 + threadIdx.x;   // 0..49151
    int lane = (idx >> 3) & 63, e = idx & 7;
    int l = lane & 15, gg = lane >> 4;
    if (idx < 16384) {
        int fi = idx >> 9, n = fi >> 2, ks = fi & 3;
        int k = ks * 32 + gg * 8 + e;
        w1f[idx] = (__bf16)w1[k * DD + n * 16 + l];
    } else {
        int j = idx - 16384;
        int fi = j >> 9, n = fi >> 3, ks = fi & 7;
        int k = ks * 32 + gg * 8 + e;
        w3f[j] = (__bf16)w3[k * DD + n * 16 + l];
    }
}

// ---- K1: 16 bn per block, 4 pipelined groups of 4 bn. w1 staged ONCE into LDS
// (B-frags via DS pipe - no L1/L2 B-traffic). Double-buffered raw-adj bf16 + ave
// LDS buffers; register prefetch of group g+1 issued before group g's barriers.
__launch_bounds__(256, 2)
__global__ void k_att(const float* __restrict__ ave, const float* __restrict__ adj,
                      const float* __restrict__ wgt, const float* __restrict__ w1,
                      const float* __restrict__ w2, const __bf16* __restrict__ w1f,
                      float* __restrict__ att_out) {
    __shared__ unsigned char lds[59584];
    __bf16* w1s = (__bf16*)lds;                               // 32 KB
    // bufA[b]: 48 rows x 256B raw adj bf16, XOR-swizzled     (lds + 32768 + b*12288)
    // bufV[b]: 4 rows x 256B ave bf16                        (lds + 57344 + b*1024)
    float* sco = (float*)(lds + 59392);                       // 48 scores

    const int t = threadIdx.x;
    const int lane = t & 63;
    const int w = t >> 6;                  // wave 0..3
    const int l = lane & 15, gq = lane >> 4;
    const int bn_base = blockIdx.x * 16;

    // ---- stage w1f -> LDS once (coalesced; visible after first B1 barrier) ----
    {
        const f32x4* src = (const f32x4*)w1f;
        f32x4* dst = (f32x4*)w1s;
        #pragma unroll
        for (int p = 0; p < 8; ++p) dst[p * 256 + t] = src[p * 256 + t];
    }

    // ---- register prefetch of one group's 48 adj rows + 4 ave rows ----
    f32x4 pa[6], pe0, pe1;
    const int s_row = t >> 4, s_c8 = t & 15;       // staging coords (row/16-chunk)
    #define ISSUE(G) do {                                                         \
        size_t rb_ = ((size_t)bn_base + (G) * 4) * KADJ;                          \
        _Pragma("unroll")                                                         \
        for (int i_ = 0; i_ < 3; ++i_) {                                          \
            const float* gs_ = adj + (rb_ + i_ * 16 + s_row) * DD + s_c8 * 8;     \
            pa[2 * i_]     = *reinterpret_cast<const f32x4*>(gs_);                \
            pa[2 * i_ + 1] = *reinterpret_cast<const f32x4*>(gs_ + 4);            \
        }                                                                         \
        if (t < 64) {                                                             \
            const float* as_ = ave + ((size_t)bn_base + (G) * 4 + (t >> 4)) * DD  \
                               + (t & 15) * 8;                                    \
            pe0 = *reinterpret_cast<const f32x4*>(as_);                           \
            pe1 = *reinterpret_cast<const f32x4*>(as_ + 4);                       \
        }                                                                         \
    } while (0)

    ISSUE(0);

    #pragma unroll 1
    for (int gi = 0; gi < 4; ++gi) {
        unsigned char* bufA = lds + 32768 + (gi & 1) * 12288;
        unsigned char* bufV = lds + 57344 + (gi & 1) * 1024;

        // ---- write staged regs -> LDS (raw adj bf16, swizzled; ave bf16) ----
        #pragma unroll
        for (int i = 0; i < 3; ++i) {
            int row = i * 16 + s_row;
            *reinterpret_cast<bf16x8*>(
                bufA + row * 256 + ((s_c8 ^ (row & 15)) << 4)) =
                cvt8(pa[2 * i], pa[2 * i + 1]);
        }
        if (t < 64)
            *reinterpret_cast<bf16x8*>(bufV + (t >> 4) * 256 + (t & 15) * 16) =
                cvt8(pe0, pe1);
        if (gi < 3) ISSUE(gi + 1);       // fire next group's loads into the pipe
        __syncthreads();                 // B1: staging (and w1s on gi=0) visible

        // ---- phase 2: waves 0..2 -> 16-row tile each (48 real rows) ----
        if (w < 3) {
            const int lr = w * 16 + l;
            const int bnl = lr / 12;               // local bn of this row (0..3)
            f32x4 acc[8];
            #pragma unroll
            for (int n = 0; n < 8; ++n) acc[n] = f32x4{0.f, 0.f, 0.f, 0.f};
            #pragma unroll 1
            for (int ks = 0; ks < 4; ++ks) {
                bf16x8 adjf = *reinterpret_cast<const bf16x8*>(
                    bufA + lr * 256 + (((ks * 4 + gq) ^ (lr & 15)) << 4));
                bf16x8 avef = *reinterpret_cast<const bf16x8*>(
                    bufV + bnl * 256 + ks * 64 + gq * 16);
                bf16x8 af = mul8(adjf, avef);
                #pragma unroll
                for (int n = 0; n < 8; ++n) {
                    bf16x8 bq = *reinterpret_cast<const bf16x8*>(
                        w1s + (size_t)(n * 4 + ks) * 512 + lane * 8);
                    acc[n] = __builtin_amdgcn_mfma_f32_16x16x32_bf16(af, bq, acc[n], 0, 0, 0);
                }
            }
            // epilogue: rank-1 wgt column, leaky, dot w2
            float wv[4];
            #pragma unroll
            for (int j = 0; j < 4; ++j)
                wv[j] = wgt[((size_t)bn_base + gi * 4) * KADJ + w * 16 + gq * 4 + j];
            float p[4] = {0.f, 0.f, 0.f, 0.f};
            #pragma unroll
            for (int n = 0; n < 8; ++n) {
                float w1rn = w1[128 * DD + n * 16 + l];
                float w2vn = w2[n * 16 + l];
                #pragma unroll
                for (int j = 0; j < 4; ++j) {
                    float h = fmaf(wv[j], w1rn, acc[n][j]);
                    h = h > 0.f ? h : 0.2f * h;
                    p[j] = fmaf(h, w2vn, p[j]);
                }
            }
            #pragma unroll
            for (int j = 0; j < 4; ++j) {
                p[j] += __shfl_xor(p[j], 1, 64);
                p[j] += __shfl_xor(p[j], 2, 64);
                p[j] += __shfl_xor(p[j], 4, 64);
                p[j] += __shfl_xor(p[j], 8, 64);
            }
            if (l == 0)
                *reinterpret_cast<f32x4*>(&sco[w * 16 + gq * 4]) =
                    f32x4{p[0], p[1], p[2], p[3]};
        }
        __syncthreads();                 // B2: scores visible

        // ---- phase 3: wave w -> bn gi*4+w; softmax + att from LDS raw adj ----
        {
            float s[KADJ];
            float mx = -1e30f;
            #pragma unroll
            for (int k = 0; k < KADJ; ++k) { s[k] = sco[w * 12 + k]; mx = fmaxf(mx, s[k]); }
            float ssum = 0.f;
            #pragma unroll
            for (int k = 0; k < KADJ; ++k) { s[k] = __expf(s[k] - mx); ssum += s[k]; }
            float inv = 1.f / ssum;
            float a0 = 0.f, a1 = 0.f;
            #pragma unroll
            for (int k = 0; k < KADJ; ++k) {
                int row = w * 12 + k;
                u32 pk = *reinterpret_cast<const u32*>(
                    bufA + row * 256 + (((lane >> 2) ^ (row & 15)) << 4) + (lane & 3) * 4);
                float alpha = s[k] * inv;
                float e0 = __builtin_bit_cast(float, pk << 16);
                float e1 = __builtin_bit_cast(float, pk & 0xFFFF0000u);
                a0 = fmaf(alpha, e0, a0);
                a1 = fmaf(alpha, e1, a1);
            }
            *reinterpret_cast<f32x2*>(
                att_out + ((size_t)bn_base + gi * 4 + w) * DD + lane * 2) = f32x2{a0, a1};
        }
    }
    #undef ISSUE
}

// ---- K2: out = relu([itm | att] @ w3) via MFMA; B-frags coalesced from w3f ----
__launch_bounds__(256)
__global__ void k_out(const float* __restrict__ itm, const float* att,
                      const __bf16* __restrict__ w3f, float* outp) {
    const int t = threadIdx.x;
    const int lane = t & 63;
    const int w = t >> 6;
    const int l = lane & 15, g = lane >> 4;
    const int R0 = blockIdx.x * 64 + w * 16;
    const int row = R0 + l;

    bf16x8 afr[8];
    const float* ip = itm + (size_t)row * DD;
    #pragma unroll
    for (int s = 0; s < 4; ++s) {
        int c = s * 32 + g * 8;
        f32x4 a0 = *reinterpret_cast<const f32x4*>(ip + c);
        f32x4 a1 = *reinterpret_cast<const f32x4*>(ip + c + 4);
        afr[s] = cvt8(a0, a1);
    }
    const float* ap = att + (size_t)row * DD;
    #pragma unroll
    for (int s = 0; s < 4; ++s) {
        int c = s * 32 + g * 8;
        f32x4 a0 = *reinterpret_cast<const f32x4*>(ap + c);
        f32x4 a1 = *reinterpret_cast<const f32x4*>(ap + c + 4);
        afr[4 + s] = cvt8(a0, a1);
    }

    f32x4 acc[8];
    #pragma unroll
    for (int n = 0; n < 8; ++n) acc[n] = f32x4{0.f, 0.f, 0.f, 0.f};
    #pragma unroll
    for (int s = 0; s < 8; ++s) {
        const __bf16* bp = w3f + ((size_t)s * 64 + lane) * 8;    // coalesced 1KB/wave
        #pragma unroll
        for (int n = 0; n < 8; ++n) {
            bf16x8 bfr = *reinterpret_cast<const bf16x8*>(bp + (size_t)n * 4096);
            acc[n] = __builtin_amdgcn_mfma_f32_16x16x32_bf16(afr[s], bfr, acc[n], 0, 0, 0);
        }
    }

    #pragma unroll
    for (int n = 0; n < 8; ++n) {
        #pragma unroll
        for (int j = 0; j < 4; ++j)
            outp[(size_t)(R0 + g * 4 + j) * DD + n * 16 + l] = fmaxf(acc[n][j], 0.f);
    }
}

extern "C" void kernel_launch(void* const* d_in, const int* in_sizes, int n_in,
                              void* d_out, int out_size, void* d_ws, size_t ws_size,
                              hipStream_t stream) {
    const float* itm = (const float*)d_in[1];
    const float* ave = (const float*)d_in[2];
    const float* adj = (const float*)d_in[3];
    const float* wgt = (const float*)d_in[4];
    const float* w1  = (const float*)d_in[5];
    const float* w2  = (const float*)d_in[6];
    const float* w3  = (const float*)d_in[7];
    float* outp = (float*)d_out;

    __bf16* w1f = (__bf16*)d_ws;                       // 32 KB, fragment-ordered
    __bf16* w3f = (__bf16*)((char*)d_ws + 32 * 1024);  // 64 KB, fragment-ordered

    k_prep<<<dim3(192), dim3(256), 0, stream>>>(w1, w3, w1f, w3f);
    k_att<<<dim3(BN_TOTAL / 16), dim3(256), 0, stream>>>(ave, adj, wgt, w1, w2, w1f, outp);
    k_out<<<dim3(BN_TOTAL / 64), dim3(256), 0, stream>>>(itm, outp, w3f, outp);
}